// Round 11
// baseline (10580.672 us; speedup 1.0000x reference)
//
#include <hip/hip_runtime.h>

// LSTM T=4096, I=512, H=2048, 4H=8192, O=1, fp32.
// R23 = R22 resubmitted verbatim (R10 bench was an infra failure:
// "MI355X container failed twice" — no verdict on the kernel itself;
// fold32/permlane audit found no defect, poll guard bounds all spins).
// R22 = R21 (champion, 9531us: R12 ring + parallel-activation tail +
// split-bf16 MFMA gemm) + ONE isolated delta: permlane32 pre-fold.
// R21 proved post-B2 tail latency counts 1:1 in the step period. Next
// biggest tail item: 16x ds_read_b128 + 64 adds (part reduce, ~190cy+).
// Fold kc with kc^32 BEFORE B2 via v_permlane32_swap (pure VALU, no LDS
// pipe -- R15's ds_swizzle butterfly regression was LDS-pipe contention),
// halving the tail reduce to 8x b128 + 32 adds. part[32x132] -> [32x68].
// Everything else (poll + s_sleep(1)/(8), publish, activations, gemm)
// is R21-exact.
// h published as tagged u64 (fp32bits<<32 | step), parity double buffer.

#define T_STEPS 4096
#define HID     2048
#define GATES   8192
#define KIN     512
#define NWG     256
#define NTHR    512
#define NREP    4
#define XG_BYTES ((size_t)T_STEPS * GATES * 4)
#define HCOM_BYTES ((size_t)NREP * 2 * HID * 8)   // 128 KB

typedef float v2f __attribute__((ext_vector_type(2)));
typedef __attribute__((ext_vector_type(8))) short bf16x8;   // 8 bf16 (4 VGPRs)
typedef __attribute__((ext_vector_type(4))) float f32x4a;   // MFMA acc

__device__ __forceinline__ float u2f(unsigned int u) {
    union { unsigned int u; float f; } x; x.u = u; return x.f;
}
__device__ __forceinline__ float fast_sigmoid(float x) {
    return 1.f / (1.f + __expf(-x));
}
__device__ __forceinline__ float fast_tanh(float x) {
    return 2.f / (1.f + __expf(-2.f * x)) - 1.f;
}
__device__ __forceinline__ unsigned short f2bf(float f) {   // RNE f32->bf16
    unsigned int u = __float_as_uint(f);
    unsigned int r = u + 0x7FFFu + ((u >> 16) & 1u);
    return (unsigned short)(r >> 16);
}
__device__ __forceinline__ float bf2f(unsigned short h) {
    return __uint_as_float(((unsigned int)h) << 16);
}
// fold x with lane^32 partner: both outputs of permlane32_swap summed give
// x[l] + x[l^32] in every lane (orientation-independent). Pure VALU.
__device__ __forceinline__ float fold32(float x) {
    unsigned int u = __float_as_uint(x);
    auto r = __builtin_amdgcn_permlane32_swap(u, u, false, false);
    return __uint_as_float(r[0]) + __uint_as_float(r[1]);
}

// ---------------- xg = X @ Wih^T + (bih+bhh), split-bf16 MFMA ----------------
// (R18-verified, unchanged)
__global__ __launch_bounds__(256) void gemm_xg(const float* __restrict__ A,
                                               const float* __restrict__ B,
                                               const float* __restrict__ bih,
                                               const float* __restrict__ bhh,
                                               float* __restrict__ C) {
    __shared__ unsigned short Ah[64][40], Al[64][40];
    __shared__ unsigned short Bh[64][40], Bl[64][40];
    const int t  = threadIdx.x;
    const int l  = t & 63;
    const int w  = t >> 6;
    const int wm = w >> 1, wn = w & 1;
    const int m0 = blockIdx.y * 64, n0 = blockIdx.x * 64;
    const int sr = t >> 3;          // 0..31 (stage row; +32 for second half)
    const int sc = (t & 7) * 4;     // 0..28 (stage col, 4 floats)
    const int lr = l & 15;          // frag row/col within 16
    const int kq = (l >> 4) * 8;    // frag k-offset

    f32x4a acc[2][2] = {};

    for (int k0 = 0; k0 < KIN; k0 += 32) {
        float4 a0 = *(const float4*)(A + (size_t)(m0 + sr)      * KIN + k0 + sc);
        float4 a1 = *(const float4*)(A + (size_t)(m0 + sr + 32) * KIN + k0 + sc);
        float4 b0 = *(const float4*)(B + (size_t)(n0 + sr)      * KIN + k0 + sc);
        float4 b1 = *(const float4*)(B + (size_t)(n0 + sr + 32) * KIN + k0 + sc);
        __syncthreads();            // protect previous iter's frag reads
        {
            ushort4 h, lo;
            h.x = f2bf(a0.x); lo.x = f2bf(a0.x - bf2f(h.x));
            h.y = f2bf(a0.y); lo.y = f2bf(a0.y - bf2f(h.y));
            h.z = f2bf(a0.z); lo.z = f2bf(a0.z - bf2f(h.z));
            h.w = f2bf(a0.w); lo.w = f2bf(a0.w - bf2f(h.w));
            *(ushort4*)&Ah[sr][sc] = h; *(ushort4*)&Al[sr][sc] = lo;
            h.x = f2bf(a1.x); lo.x = f2bf(a1.x - bf2f(h.x));
            h.y = f2bf(a1.y); lo.y = f2bf(a1.y - bf2f(h.y));
            h.z = f2bf(a1.z); lo.z = f2bf(a1.z - bf2f(h.z));
            h.w = f2bf(a1.w); lo.w = f2bf(a1.w - bf2f(h.w));
            *(ushort4*)&Ah[sr + 32][sc] = h; *(ushort4*)&Al[sr + 32][sc] = lo;
            h.x = f2bf(b0.x); lo.x = f2bf(b0.x - bf2f(h.x));
            h.y = f2bf(b0.y); lo.y = f2bf(b0.y - bf2f(h.y));
            h.z = f2bf(b0.z); lo.z = f2bf(b0.z - bf2f(h.z));
            h.w = f2bf(b0.w); lo.w = f2bf(b0.w - bf2f(h.w));
            *(ushort4*)&Bh[sr][sc] = h; *(ushort4*)&Bl[sr][sc] = lo;
            h.x = f2bf(b1.x); lo.x = f2bf(b1.x - bf2f(h.x));
            h.y = f2bf(b1.y); lo.y = f2bf(b1.y - bf2f(h.y));
            h.z = f2bf(b1.z); lo.z = f2bf(b1.z - bf2f(h.z));
            h.w = f2bf(b1.w); lo.w = f2bf(b1.w - bf2f(h.w));
            *(ushort4*)&Bh[sr + 32][sc] = h; *(ushort4*)&Bl[sr + 32][sc] = lo;
        }
        __syncthreads();            // tiles ready

        bf16x8 ah[2], al2[2], bh2[2], bl2[2];
#pragma unroll
        for (int fr = 0; fr < 2; ++fr) {
            const int ar = wm * 32 + fr * 16 + lr;
            ah[fr]  = *(const bf16x8*)&Ah[ar][kq];
            al2[fr] = *(const bf16x8*)&Al[ar][kq];
            const int br = wn * 32 + fr * 16 + lr;
            bh2[fr] = *(const bf16x8*)&Bh[br][kq];
            bl2[fr] = *(const bf16x8*)&Bl[br][kq];
        }
#pragma unroll
        for (int fr = 0; fr < 2; ++fr)
#pragma unroll
            for (int fc = 0; fc < 2; ++fc) {
                acc[fr][fc] = __builtin_amdgcn_mfma_f32_16x16x32_bf16(
                    ah[fr], bh2[fc], acc[fr][fc], 0, 0, 0);
                acc[fr][fc] = __builtin_amdgcn_mfma_f32_16x16x32_bf16(
                    ah[fr], bl2[fc], acc[fr][fc], 0, 0, 0);
                acc[fr][fc] = __builtin_amdgcn_mfma_f32_16x16x32_bf16(
                    al2[fr], bh2[fc], acc[fr][fc], 0, 0, 0);
            }
    }

    // epilogue: bias + unpacked store (same layout R12's lstm reads)
#pragma unroll
    for (int fc = 0; fc < 2; ++fc) {
        const int col = n0 + wn * 32 + fc * 16 + lr;
        const float bs = bih[col] + bhh[col];
#pragma unroll
        for (int fr = 0; fr < 2; ++fr) {
            const int rowb = m0 + wm * 32 + fr * 16 + (l >> 4) * 4;
#pragma unroll
            for (int j = 0; j < 4; ++j)
                C[(size_t)(rowb + j) * GATES + col] = acc[fr][fc][j] + bs;
        }
    }
}

// ---------------- persistent recurrence (R21 + permlane32 pre-fold) ---------
// 256 WGs x 512 thr. WG owns hidden [8b,8b+8) = 32 gate rows.
// kc=t&127 (k subset {g*128+kc}), rg=t>>7 gate group, 8 rows each.
// Waves 0-1 poll replica (wg&3) + rebroadcast via LDS; tail on wave 0.
// hcom layout: replica r, parity p at hcom + (r*2+p)*HID.
template<int USE_XG>
__global__ __launch_bounds__(NTHR, 2) void lstm_rec(
    const float* __restrict__ X,
    const float* __restrict__ Wih,
    const float* __restrict__ xg,
    const float* __restrict__ Whh,
    const float* __restrict__ bih,
    const float* __restrict__ bhh,
    unsigned long long* __restrict__ hcom)
{
    const int t  = threadIdx.x;
    const int kc = t & 127;
    const int rg = t >> 7;
    const int j0 = blockIdx.x * 8;
    const int rep = blockIdx.x & (NREP - 1);

    // register-resident W_hh slice, packed as float2 pairs over g
    v2f whh2[8][8];
#pragma unroll
    for (int m = 0; m < 8; ++m) {
        const float* wr = Whh + (size_t)(rg * HID + j0 + m) * HID + kc;
#pragma unroll
        for (int j = 0; j < 8; ++j) {
            v2f p; p.x = wr[(2 * j) * 128]; p.y = wr[(2 * j + 1) * 128];
            whh2[m][j] = p;
        }
    }
    float wih[8][4];
    if (!USE_XG) {
#pragma unroll
        for (int m = 0; m < 8; ++m) {
            float4 vx = *(const float4*)(Wih + (size_t)(rg * HID + j0 + m) * KIN + kc * 4);
            wih[m][0] = vx.x; wih[m][1] = vx.y; wih[m][2] = vx.z; wih[m][3] = vx.w;
        }
    }

    float brow = 0.f;
    if (t < 32) {
        const int grow = (t >> 3) * HID + j0 + (t & 7);
        brow = bih[grow] + bhh[grow];
    }

    __shared__ float hshare[HID];
    __shared__ float part[32 * 68];
    float c_state = 0.f;

    for (int s = 0; s < T_STEPS; ++s) {
        // prefetch xg (reducer rows) before the poll — hides HBM/LLC latency
        float xgv = 0.f;
        if (USE_XG && t < 32)
            xgv = xg[(size_t)s * GATES + (t >> 3) * HID + j0 + (t & 7)];

        v2f hv2[8];
        if (t < 128) {
            // Wave 1 delays its first round past the publish window; wave 0's
            // tail provides that delay naturally. (R11 lesson.)
            if (t >= 64 && s > 0) __builtin_amdgcn_s_sleep(8);
            // poll my replica's 16 tagged words (parity s&1)
            const unsigned long long* hp = hcom + ((size_t)rep * 2 + (s & 1)) * HID;
            unsigned long long v[16];
            int guard = 1 << 18;
            for (;;) {
#pragma unroll
                for (int g = 0; g < 16; ++g)
                    v[g] = __hip_atomic_load(hp + g * 128 + kc, __ATOMIC_RELAXED,
                                             __HIP_MEMORY_SCOPE_AGENT);
                bool ok = true;
#pragma unroll
                for (int g = 0; g < 16; ++g)
                    ok &= ((unsigned int)v[g] >= (unsigned int)s);
                if (ok || --guard <= 0) break;
                __builtin_amdgcn_s_sleep(1);   // load-bearing: duty-cycle gap
                                               // lets publisher stores win LLC
                                               // arbitration (R19: removing it
                                               // cost ~180cy/step)
            }
#pragma unroll
            for (int j = 0; j < 8; ++j) {
                v2f p;
                p.x = u2f((unsigned int)(v[2 * j] >> 32));
                p.y = u2f((unsigned int)(v[2 * j + 1] >> 32));
                hv2[j] = p;
                hshare[(2 * j) * 128 + kc]     = p.x;
                hshare[(2 * j + 1) * 128 + kc] = p.y;
            }
        }
        __syncthreads();                     // B1: hshare ready
        if (t >= 128) {
#pragma unroll
            for (int j = 0; j < 8; ++j) {
                v2f p;
                p.x = hshare[(2 * j) * 128 + kc];
                p.y = hshare[(2 * j + 1) * 128 + kc];
                hv2[j] = p;
            }
        }

        v2f acc2[8];
        if (!USE_XG) {
            float4 x4 = *(const float4*)(X + (size_t)s * KIN + kc * 4);
#pragma unroll
            for (int m = 0; m < 8; ++m) {
                float a = wih[m][0] * x4.x;
                a = fmaf(wih[m][1], x4.y, a);
                a = fmaf(wih[m][2], x4.z, a);
                a = fmaf(wih[m][3], x4.w, a);
                v2f z; z.x = a; z.y = 0.f; acc2[m] = z;
            }
        } else {
#pragma unroll
            for (int m = 0; m < 8; ++m) { v2f z; z.x = 0.f; z.y = 0.f; acc2[m] = z; }
        }

        // packed dot: 64 v_pk_fma_f32 per thread
#pragma unroll
        for (int m = 0; m < 8; ++m) {
            v2f a = acc2[m];
#pragma unroll
            for (int j = 0; j < 8; ++j)
                a = __builtin_elementwise_fma(whh2[m][j], hv2[j], a);
            acc2[m] = a;
        }

        // permlane32 pre-fold: sum kc with kc^32 partner (same wave, pure
        // VALU) -> only kc&32==0 lanes write -> part rows halve to 64 entries.
        float fsum[8];
#pragma unroll
        for (int m = 0; m < 8; ++m)
            fsum[m] = fold32(acc2[m].x + acc2[m].y);
        if ((kc & 32) == 0) {
            const int fidx = (kc & 31) + ((kc >> 6) << 5);   // 0..63
#pragma unroll
            for (int m = 0; m < 8; ++m)
                part[(rg * 8 + m) * 68 + fidx] = fsum[m];
        }
        __syncthreads();                     // B2: partials ready

        // tail: 64 threads reduce (2 per row, 32 floats each), shuffle
        // combine, parallel activations (R21), 8 threads gate + publish.
        if (t < 64) {
            const int row = t & 31, half = t >> 5;
            const float4* p4 = (const float4*)(part + row * 68 + half * 32);
            float s0 = 0.f, s1 = 0.f, s2 = 0.f, s3 = 0.f;
#pragma unroll
            for (int i = 0; i < 8; ++i) {
                float4 pv = p4[i];
                s0 += pv.x; s1 += pv.y; s2 += pv.z; s3 += pv.w;
            }
            float sum = (s0 + s1) + (s2 + s3);
            sum += __shfl_xor(sum, 32, 64);  // combine the two halves
            sum += brow + xgv;               // valid on t<32 (rows)
            const bool isG = (t >= 16) && (t < 24);
            const float scl = isG ? -2.f : -1.f;
            const float num = isG ?  2.f :  1.f;
            const float off = isG ? -1.f :  0.f;
            const float act = num / (1.f + __expf(scl * sum)) + off; // t<32
            const float f_s = __shfl_down(act, 8, 64);
            const float g_t = __shfl_down(act, 16, 64);
            const float o_s = __shfl_down(act, 24, 64);
            if (t < 8) {
                c_state = f_s * c_state + act * g_t;   // act = i gate (row t)
                const float h = o_s * fast_tanh(c_state);
                const unsigned long long pk =
                    ((unsigned long long)__float_as_uint(h) << 32) | (unsigned int)(s + 1);
                const size_t slot = (size_t)((s + 1) & 1) * HID + j0 + t;
#pragma unroll
                for (int r = 0; r < NREP; ++r)
                    __hip_atomic_store(&hcom[(size_t)r * 2 * HID + slot], pk,
                                       __ATOMIC_RELAXED, __HIP_MEMORY_SCOPE_AGENT);
            }
        }
        // reuse safety (per replica): overwriting parity-p slot s with s+2
        // requires THIS WG to pass poll(s+1), which requires every WG
        // (incl. any reader still at step s) to have published s+1 — which
        // they only do after finishing step s. Same invariant as R11.
    }
}

// ---------------- out[0] = h_T . W_lin + b_lin ----------------
__global__ __launch_bounds__(256) void final_linear(const unsigned long long* __restrict__ hcom,
                                                    const float* __restrict__ Wlin,
                                                    const float* __restrict__ blin,
                                                    float* __restrict__ out) {
    __shared__ float red[4];
    const int t = threadIdx.x;
    float a = 0.f;
#pragma unroll
    for (int e = 0; e < 8; ++e) {
        const int idx = t * 8 + e;   // replica 0, parity 0 holds h_T (tag 4096)
        a = fmaf(Wlin[idx], u2f((unsigned int)(hcom[idx] >> 32)), a);
    }
#pragma unroll
    for (int m = 1; m < 64; m <<= 1) a += __shfl_xor(a, m, 64);
    if ((t & 63) == 0) red[t >> 6] = a;
    __syncthreads();
    if (t == 0) out[0] = red[0] + red[1] + red[2] + red[3] + blin[0];
}

extern "C" void kernel_launch(void* const* d_in, const int* in_sizes, int n_in,
                              void* d_out, int out_size, void* d_ws, size_t ws_size,
                              hipStream_t stream) {
    const float* X    = (const float*)d_in[0];
    const float* Wih  = (const float*)d_in[1];
    const float* Whh  = (const float*)d_in[2];
    const float* bih  = (const float*)d_in[3];
    const float* bhh  = (const float*)d_in[4];
    const float* Wlin = (const float*)d_in[5];
    const float* blin = (const float*)d_in[6];
    float* out = (float*)d_out;

    char* ws = (char*)d_ws;
    const bool big = ws_size >= XG_BYTES + HCOM_BYTES;

    if (big) {
        float* xg = (float*)ws;
        unsigned long long* hcom = (unsigned long long*)(ws + XG_BYTES);
        (void)hipMemsetAsync(hcom, 0, HCOM_BYTES, stream);
        gemm_xg<<<dim3(GATES / 64, T_STEPS / 64), 256, 0, stream>>>(X, Wih, bih, bhh, xg);
        lstm_rec<1><<<dim3(NWG), dim3(NTHR), 0, stream>>>(X, Wih, xg, Whh, bih, bhh, hcom);
        final_linear<<<1, 256, 0, stream>>>(hcom, Wlin, blin, out);
    } else {
        unsigned long long* hcom = (unsigned long long*)ws;
        (void)hipMemsetAsync(hcom, 0, HCOM_BYTES, stream);
        lstm_rec<0><<<dim3(NWG), dim3(NTHR), 0, stream>>>(X, Wih, nullptr, Whh, bih, bhh, hcom);
        final_linear<<<1, 256, 0, stream>>>(hcom, Wlin, blin, out);
    }
}

// Round 12
// 9515.157 us; speedup vs baseline: 1.1120x; 1.1120x over previous
//
#include <hip/hip_runtime.h>

// LSTM T=4096, I=512, H=2048, 4H=8192, O=1, fp32.
// R24 = FINAL: bit-exact restore of R21 (champion, 9531us measured).
// Session conclusions baked into this kernel:
//  * R12 ring structure (2 polling waves + hshare + B1, part[] + B2,
//    wave-0 tail, NREP=4 coalesced publish, s_sleep(1) poll gap +
//    wave-1 s_sleep(8) desync) is a sharp local optimum: scatter publish
//    (R13), predicated poll (R14), shuffle tail (R15), all-waves-poll (R16),
//    pipelined poll (R17), sleep removal (R19), permlane pre-fold (R23)
//    ALL regressed. Cross-lane ops pre-B2 cost 3-6x nominal (R15+R23).
//  * Post-B2 tail latency counts 1:1 in the step period: parallel
//    activations (R21, -750us) and split-bf16 MFMA gemm (R18, -320us)
//    are the two session wins.
// h published as tagged u64 (fp32bits<<32 | step), parity double buffer.

#define T_STEPS 4096
#define HID     2048
#define GATES   8192
#define KIN     512
#define NWG     256
#define NTHR    512
#define NREP    4
#define XG_BYTES ((size_t)T_STEPS * GATES * 4)
#define HCOM_BYTES ((size_t)NREP * 2 * HID * 8)   // 128 KB

typedef float v2f __attribute__((ext_vector_type(2)));
typedef __attribute__((ext_vector_type(8))) short bf16x8;   // 8 bf16 (4 VGPRs)
typedef __attribute__((ext_vector_type(4))) float f32x4a;   // MFMA acc

__device__ __forceinline__ float u2f(unsigned int u) {
    union { unsigned int u; float f; } x; x.u = u; return x.f;
}
__device__ __forceinline__ float fast_sigmoid(float x) {
    return 1.f / (1.f + __expf(-x));
}
__device__ __forceinline__ float fast_tanh(float x) {
    return 2.f / (1.f + __expf(-2.f * x)) - 1.f;
}
__device__ __forceinline__ unsigned short f2bf(float f) {   // RNE f32->bf16
    unsigned int u = __float_as_uint(f);
    unsigned int r = u + 0x7FFFu + ((u >> 16) & 1u);
    return (unsigned short)(r >> 16);
}
__device__ __forceinline__ float bf2f(unsigned short h) {
    return __uint_as_float(((unsigned int)h) << 16);
}

// ---------------- xg = X @ Wih^T + (bih+bhh), split-bf16 MFMA ----------------
// C[m][n] = sum_k X[m][k] * Wih[n][k]  (B^T gemm: both inputs K-contiguous).
// 64x64 tile, 4 waves, wave (wm,wn) owns a 32x32 quadrant = 2x2 frags of
// 16x16x32_bf16. Split each f32 v into hi=bf16(v), lo=bf16(v-hi); accumulate
// hi*hi + hi*lo + lo*hi (drop lo*lo ~2^-34). Fragment maps (guide-verified):
//   A: row=lane&15, k=(lane>>4)*8+i    B: col=lane&15, k=(lane>>4)*8+i
//   C: col=lane&15, row=(lane>>4)*4+reg   (m89)
// LDS pitch 40 bf16 (80B rows): frag b128 reads land 2 lanes/bank (free).
__global__ __launch_bounds__(256) void gemm_xg(const float* __restrict__ A,
                                               const float* __restrict__ B,
                                               const float* __restrict__ bih,
                                               const float* __restrict__ bhh,
                                               float* __restrict__ C) {
    __shared__ unsigned short Ah[64][40], Al[64][40];
    __shared__ unsigned short Bh[64][40], Bl[64][40];
    const int t  = threadIdx.x;
    const int l  = t & 63;
    const int w  = t >> 6;
    const int wm = w >> 1, wn = w & 1;
    const int m0 = blockIdx.y * 64, n0 = blockIdx.x * 64;
    const int sr = t >> 3;          // 0..31 (stage row; +32 for second half)
    const int sc = (t & 7) * 4;     // 0..28 (stage col, 4 floats)
    const int lr = l & 15;          // frag row/col within 16
    const int kq = (l >> 4) * 8;    // frag k-offset

    f32x4a acc[2][2] = {};

    for (int k0 = 0; k0 < KIN; k0 += 32) {
        float4 a0 = *(const float4*)(A + (size_t)(m0 + sr)      * KIN + k0 + sc);
        float4 a1 = *(const float4*)(A + (size_t)(m0 + sr + 32) * KIN + k0 + sc);
        float4 b0 = *(const float4*)(B + (size_t)(n0 + sr)      * KIN + k0 + sc);
        float4 b1 = *(const float4*)(B + (size_t)(n0 + sr + 32) * KIN + k0 + sc);
        __syncthreads();            // protect previous iter's frag reads
        {
            ushort4 h, lo;
            h.x = f2bf(a0.x); lo.x = f2bf(a0.x - bf2f(h.x));
            h.y = f2bf(a0.y); lo.y = f2bf(a0.y - bf2f(h.y));
            h.z = f2bf(a0.z); lo.z = f2bf(a0.z - bf2f(h.z));
            h.w = f2bf(a0.w); lo.w = f2bf(a0.w - bf2f(h.w));
            *(ushort4*)&Ah[sr][sc] = h; *(ushort4*)&Al[sr][sc] = lo;
            h.x = f2bf(a1.x); lo.x = f2bf(a1.x - bf2f(h.x));
            h.y = f2bf(a1.y); lo.y = f2bf(a1.y - bf2f(h.y));
            h.z = f2bf(a1.z); lo.z = f2bf(a1.z - bf2f(h.z));
            h.w = f2bf(a1.w); lo.w = f2bf(a1.w - bf2f(h.w));
            *(ushort4*)&Ah[sr + 32][sc] = h; *(ushort4*)&Al[sr + 32][sc] = lo;
            h.x = f2bf(b0.x); lo.x = f2bf(b0.x - bf2f(h.x));
            h.y = f2bf(b0.y); lo.y = f2bf(b0.y - bf2f(h.y));
            h.z = f2bf(b0.z); lo.z = f2bf(b0.z - bf2f(h.z));
            h.w = f2bf(b0.w); lo.w = f2bf(b0.w - bf2f(h.w));
            *(ushort4*)&Bh[sr][sc] = h; *(ushort4*)&Bl[sr][sc] = lo;
            h.x = f2bf(b1.x); lo.x = f2bf(b1.x - bf2f(h.x));
            h.y = f2bf(b1.y); lo.y = f2bf(b1.y - bf2f(h.y));
            h.z = f2bf(b1.z); lo.z = f2bf(b1.z - bf2f(h.z));
            h.w = f2bf(b1.w); lo.w = f2bf(b1.w - bf2f(h.w));
            *(ushort4*)&Bh[sr + 32][sc] = h; *(ushort4*)&Bl[sr + 32][sc] = lo;
        }
        __syncthreads();            // tiles ready

        bf16x8 ah[2], al2[2], bh2[2], bl2[2];
#pragma unroll
        for (int fr = 0; fr < 2; ++fr) {
            const int ar = wm * 32 + fr * 16 + lr;
            ah[fr]  = *(const bf16x8*)&Ah[ar][kq];
            al2[fr] = *(const bf16x8*)&Al[ar][kq];
            const int br = wn * 32 + fr * 16 + lr;
            bh2[fr] = *(const bf16x8*)&Bh[br][kq];
            bl2[fr] = *(const bf16x8*)&Bl[br][kq];
        }
#pragma unroll
        for (int fr = 0; fr < 2; ++fr)
#pragma unroll
            for (int fc = 0; fc < 2; ++fc) {
                acc[fr][fc] = __builtin_amdgcn_mfma_f32_16x16x32_bf16(
                    ah[fr], bh2[fc], acc[fr][fc], 0, 0, 0);
                acc[fr][fc] = __builtin_amdgcn_mfma_f32_16x16x32_bf16(
                    ah[fr], bl2[fc], acc[fr][fc], 0, 0, 0);
                acc[fr][fc] = __builtin_amdgcn_mfma_f32_16x16x32_bf16(
                    al2[fr], bh2[fc], acc[fr][fc], 0, 0, 0);
            }
    }

    // epilogue: bias + unpacked store (same layout R12's lstm reads)
#pragma unroll
    for (int fc = 0; fc < 2; ++fc) {
        const int col = n0 + wn * 32 + fc * 16 + lr;
        const float bs = bih[col] + bhh[col];
#pragma unroll
        for (int fr = 0; fr < 2; ++fr) {
            const int rowb = m0 + wm * 32 + fr * 16 + (l >> 4) * 4;
#pragma unroll
            for (int j = 0; j < 4; ++j)
                C[(size_t)(rowb + j) * GATES + col] = acc[fr][fc][j] + bs;
        }
    }
}

// ---------------- persistent recurrence (R12 + parallel-activation tail) ----
// 256 WGs x 512 thr. WG owns hidden [8b,8b+8) = 32 gate rows.
// kc=t&127 (k subset {g*128+kc}), rg=t>>7 gate group, 8 rows each.
// Waves 0-1 poll replica (wg&3) + rebroadcast via LDS; tail on wave 0.
// hcom layout: replica r, parity p at hcom + (r*2+p)*HID.
template<int USE_XG>
__global__ __launch_bounds__(NTHR, 2) void lstm_rec(
    const float* __restrict__ X,
    const float* __restrict__ Wih,
    const float* __restrict__ xg,
    const float* __restrict__ Whh,
    const float* __restrict__ bih,
    const float* __restrict__ bhh,
    unsigned long long* __restrict__ hcom)
{
    const int t  = threadIdx.x;
    const int kc = t & 127;
    const int rg = t >> 7;
    const int j0 = blockIdx.x * 8;
    const int rep = blockIdx.x & (NREP - 1);

    // register-resident W_hh slice, packed as float2 pairs over g
    v2f whh2[8][8];
#pragma unroll
    for (int m = 0; m < 8; ++m) {
        const float* wr = Whh + (size_t)(rg * HID + j0 + m) * HID + kc;
#pragma unroll
        for (int j = 0; j < 8; ++j) {
            v2f p; p.x = wr[(2 * j) * 128]; p.y = wr[(2 * j + 1) * 128];
            whh2[m][j] = p;
        }
    }
    float wih[8][4];
    if (!USE_XG) {
#pragma unroll
        for (int m = 0; m < 8; ++m) {
            float4 vx = *(const float4*)(Wih + (size_t)(rg * HID + j0 + m) * KIN + kc * 4);
            wih[m][0] = vx.x; wih[m][1] = vx.y; wih[m][2] = vx.z; wih[m][3] = vx.w;
        }
    }

    float brow = 0.f;
    if (t < 32) {
        const int grow = (t >> 3) * HID + j0 + (t & 7);
        brow = bih[grow] + bhh[grow];
    }

    __shared__ float hshare[HID];
    __shared__ float part[32 * 132];
    float c_state = 0.f;

    for (int s = 0; s < T_STEPS; ++s) {
        // prefetch xg (reducer rows) before the poll — hides HBM/LLC latency
        float xgv = 0.f;
        if (USE_XG && t < 32)
            xgv = xg[(size_t)s * GATES + (t >> 3) * HID + j0 + (t & 7)];

        v2f hv2[8];
        if (t < 128) {
            // Wave 1 delays its first round past the publish window; wave 0's
            // tail provides that delay naturally. (R11 lesson.)
            if (t >= 64 && s > 0) __builtin_amdgcn_s_sleep(8);
            // poll my replica's 16 tagged words (parity s&1)
            const unsigned long long* hp = hcom + ((size_t)rep * 2 + (s & 1)) * HID;
            unsigned long long v[16];
            int guard = 1 << 18;
            for (;;) {
#pragma unroll
                for (int g = 0; g < 16; ++g)
                    v[g] = __hip_atomic_load(hp + g * 128 + kc, __ATOMIC_RELAXED,
                                             __HIP_MEMORY_SCOPE_AGENT);
                bool ok = true;
#pragma unroll
                for (int g = 0; g < 16; ++g)
                    ok &= ((unsigned int)v[g] >= (unsigned int)s);
                if (ok || --guard <= 0) break;
                __builtin_amdgcn_s_sleep(1);   // load-bearing: duty-cycle gap
                                               // lets publisher stores win LLC
                                               // arbitration (R19: removing it
                                               // cost ~180cy/step)
            }
#pragma unroll
            for (int j = 0; j < 8; ++j) {
                v2f p;
                p.x = u2f((unsigned int)(v[2 * j] >> 32));
                p.y = u2f((unsigned int)(v[2 * j + 1] >> 32));
                hv2[j] = p;
                hshare[(2 * j) * 128 + kc]     = p.x;
                hshare[(2 * j + 1) * 128 + kc] = p.y;
            }
        }
        __syncthreads();                     // B1: hshare ready
        if (t >= 128) {
#pragma unroll
            for (int j = 0; j < 8; ++j) {
                v2f p;
                p.x = hshare[(2 * j) * 128 + kc];
                p.y = hshare[(2 * j + 1) * 128 + kc];
                hv2[j] = p;
            }
        }

        v2f acc2[8];
        if (!USE_XG) {
            float4 x4 = *(const float4*)(X + (size_t)s * KIN + kc * 4);
#pragma unroll
            for (int m = 0; m < 8; ++m) {
                float a = wih[m][0] * x4.x;
                a = fmaf(wih[m][1], x4.y, a);
                a = fmaf(wih[m][2], x4.z, a);
                a = fmaf(wih[m][3], x4.w, a);
                v2f z; z.x = a; z.y = 0.f; acc2[m] = z;
            }
        } else {
#pragma unroll
            for (int m = 0; m < 8; ++m) { v2f z; z.x = 0.f; z.y = 0.f; acc2[m] = z; }
        }

        // packed dot: 64 v_pk_fma_f32 per thread
#pragma unroll
        for (int m = 0; m < 8; ++m) {
            v2f a = acc2[m];
#pragma unroll
            for (int j = 0; j < 8; ++j)
                a = __builtin_elementwise_fma(whh2[m][j], hv2[j], a);
            acc2[m] = a;
        }
#pragma unroll
        for (int m = 0; m < 8; ++m)
            part[(rg * 8 + m) * 132 + kc] = acc2[m].x + acc2[m].y;
        __syncthreads();                     // B2: partials ready

        // tail: 64 threads reduce (2 per row), shuffle combine, then
        // PARALLEL activations: each lane t<32 applies its own row's
        // nonlinearity BEFORE the gather shuffles (rows 0-7=i:sigmoid,
        // 8-15=f:sigmoid, 16-23=g:tanh, 24-31=o:sigmoid; branch-free,
        // bit-identical to fast_sigmoid/fast_tanh), collapsing the old
        // 8-trans serial chain on t<8 into 2 parallel trans ops. (R21)
        if (t < 64) {
            const int row = t & 31, half = t >> 5;
            const float4* p4 = (const float4*)(part + row * 132 + half * 64);
            float s0 = 0.f, s1 = 0.f, s2 = 0.f, s3 = 0.f;
#pragma unroll
            for (int i = 0; i < 16; ++i) {
                float4 pv = p4[i];
                s0 += pv.x; s1 += pv.y; s2 += pv.z; s3 += pv.w;
            }
            float sum = (s0 + s1) + (s2 + s3);
            sum += __shfl_xor(sum, 32, 64);  // combine the two halves
            sum += brow + xgv;               // valid on t<32 (rows)
            const bool isG = (t >= 16) && (t < 24);
            const float scl = isG ? -2.f : -1.f;
            const float num = isG ?  2.f :  1.f;
            const float off = isG ? -1.f :  0.f;
            const float act = num / (1.f + __expf(scl * sum)) + off; // t<32
            const float f_s = __shfl_down(act, 8, 64);
            const float g_t = __shfl_down(act, 16, 64);
            const float o_s = __shfl_down(act, 24, 64);
            if (t < 8) {
                c_state = f_s * c_state + act * g_t;   // act = i gate (row t)
                const float h = o_s * fast_tanh(c_state);
                const unsigned long long pk =
                    ((unsigned long long)__float_as_uint(h) << 32) | (unsigned int)(s + 1);
                const size_t slot = (size_t)((s + 1) & 1) * HID + j0 + t;
#pragma unroll
                for (int r = 0; r < NREP; ++r)
                    __hip_atomic_store(&hcom[(size_t)r * 2 * HID + slot], pk,
                                       __ATOMIC_RELAXED, __HIP_MEMORY_SCOPE_AGENT);
            }
        }
        // reuse safety (per replica): overwriting parity-p slot s with s+2
        // requires THIS WG to pass poll(s+1), which requires every WG
        // (incl. any reader still at step s) to have published s+1 — which
        // they only do after finishing step s. Same invariant as R11.
    }
}

// ---------------- out[0] = h_T . W_lin + b_lin ----------------
__global__ __launch_bounds__(256) void final_linear(const unsigned long long* __restrict__ hcom,
                                                    const float* __restrict__ Wlin,
                                                    const float* __restrict__ blin,
                                                    float* __restrict__ out) {
    __shared__ float red[4];
    const int t = threadIdx.x;
    float a = 0.f;
#pragma unroll
    for (int e = 0; e < 8; ++e) {
        const int idx = t * 8 + e;   // replica 0, parity 0 holds h_T (tag 4096)
        a = fmaf(Wlin[idx], u2f((unsigned int)(hcom[idx] >> 32)), a);
    }
#pragma unroll
    for (int m = 1; m < 64; m <<= 1) a += __shfl_xor(a, m, 64);
    if ((t & 63) == 0) red[t >> 6] = a;
    __syncthreads();
    if (t == 0) out[0] = red[0] + red[1] + red[2] + red[3] + blin[0];
}

extern "C" void kernel_launch(void* const* d_in, const int* in_sizes, int n_in,
                              void* d_out, int out_size, void* d_ws, size_t ws_size,
                              hipStream_t stream) {
    const float* X    = (const float*)d_in[0];
    const float* Wih  = (const float*)d_in[1];
    const float* Whh  = (const float*)d_in[2];
    const float* bih  = (const float*)d_in[3];
    const float* bhh  = (const float*)d_in[4];
    const float* Wlin = (const float*)d_in[5];
    const float* blin = (const float*)d_in[6];
    float* out = (float*)d_out;

    char* ws = (char*)d_ws;
    const bool big = ws_size >= XG_BYTES + HCOM_BYTES;

    if (big) {
        float* xg = (float*)ws;
        unsigned long long* hcom = (unsigned long long*)(ws + XG_BYTES);
        (void)hipMemsetAsync(hcom, 0, HCOM_BYTES, stream);
        gemm_xg<<<dim3(GATES / 64, T_STEPS / 64), 256, 0, stream>>>(X, Wih, bih, bhh, xg);
        lstm_rec<1><<<dim3(NWG), dim3(NTHR), 0, stream>>>(X, Wih, xg, Whh, bih, bhh, hcom);
        final_linear<<<1, 256, 0, stream>>>(hcom, Wlin, blin, out);
    } else {
        unsigned long long* hcom = (unsigned long long*)ws;
        (void)hipMemsetAsync(hcom, 0, HCOM_BYTES, stream);
        lstm_rec<0><<<dim3(NWG), dim3(NTHR), 0, stream>>>(X, Wih, nullptr, Whh, bih, bhh, hcom);
        final_linear<<<1, 256, 0, stream>>>(hcom, Wlin, blin, out);
    }
}